// Round 1
// baseline (415.817 us; speedup 1.0000x reference)
//
#include <hip/hip_runtime.h>

// MultiHashtable4d: 16-level 4D hash-grid interpolation.
// One thread per (point n, level l); l is wave-uniform (from blockIdx) so
// per-level tables load via SGPRs and the direct/hash branch is uniform.
// Grid layout: blockIdx = chunk*L + l  => XCD k (= blockIdx%8) sees levels {k, k+8}
// keeping ~2 level tables (8.4MB) close to its 4MiB L2.

#define FDIM 2

__global__ __launch_bounds__(256) void mh4d_kernel(
    const float* __restrict__ xyz,     // [N,3]
    const float* __restrict__ tt,      // [N,1]
    const float* __restrict__ data,    // [L,T,FDIM]
    const float* __restrict__ bounds,  // [2,4]
    const float* __restrict__ es,      // [L,4] entrys_size
    const int*   __restrict__ en,      // [L,4] entrys_num
    const int*   __restrict__ p_sh,    // start_hash
    const int*   __restrict__ p_sf,    // start_frame
    const int*   __restrict__ p_tf,    // total_frame
    float* __restrict__ out,           // [N, L*FDIM]
    int N, int L, unsigned int T, unsigned long long M)
{
    const int l     = (int)(blockIdx.x % (unsigned)L);
    const int chunk = (int)(blockIdx.x / (unsigned)L);
    const int n     = chunk * (int)blockDim.x + (int)threadIdx.x;
    if (n >= N) return;

    const int start_hash = *p_sh;
    // reference: t - start_frame/(total_frame-1), scalar rounded to f32
    const float tshift = (float)((double)(*p_sf) / (double)(*p_tf - 1));

    // wave-uniform per-level params -> scalar loads
    const float es0 = es[l * 4 + 0], es1 = es[l * 4 + 1];
    const float es2 = es[l * 4 + 2], es3 = es[l * 4 + 3];
    const int e0 = en[l * 4 + 0], e1 = en[l * 4 + 1];
    const int e2 = en[l * 4 + 2], e3 = en[l * 4 + 3];

    const float b0 = bounds[0], b1 = bounds[1], b2 = bounds[2], b3 = bounds[3];

    const float x  = xyz[n * 3 + 0];
    const float y  = xyz[n * 3 + 1];
    const float z  = xyz[n * 3 + 2];
    const float tv = tt[n] - tshift;

    // float_xyzt = (xyzt - bounds[0]) / entrys_size  (IEEE f32 div, matches ref)
    const float f0 = (x  - b0) / es0;
    const float f1 = (y  - b1) / es1;
    const float f2 = (z  - b2) / es2;
    const float f3 = (tv - b3) / es3;

    // Corner ints: trunc(f + offset) computed IN f32 — must NOT fold to trunc(f)+1,
    // because f32 rounding of (f+1.0f) near integers changes the index like the ref does.
    int lo0 = (int)f0, hi0 = (int)(f0 + 1.0f);
    int lo1 = (int)f1, hi1 = (int)(f1 + 1.0f);
    int lo2 = (int)f2, hi2 = (int)(f2 + 1.0f);
    int lo3 = (int)f3, hi3 = (int)(f3 + 1.0f);

    // offsets from UNCLIPPED corner-0 trunc (ref computes offset before clip)
    const float o0 = f0 - (float)lo0;
    const float o1 = f1 - (float)lo1;
    const float o2 = f2 - (float)lo2;
    const float o3 = f3 - (float)lo3;

    // weights: clip(1-o,0,1) / clip(o,0,1)
    const float wx[2] = { fminf(fmaxf(1.0f - o0, 0.0f), 1.0f), fminf(fmaxf(o0, 0.0f), 1.0f) };
    const float wy[2] = { fminf(fmaxf(1.0f - o1, 0.0f), 1.0f), fminf(fmaxf(o1, 0.0f), 1.0f) };
    const float wz[2] = { fminf(fmaxf(1.0f - o2, 0.0f), 1.0f), fminf(fmaxf(o2, 0.0f), 1.0f) };
    const float wt[2] = { fminf(fmaxf(1.0f - o3, 0.0f), 1.0f), fminf(fmaxf(o3, 0.0f), 1.0f) };

    // clip indices to [0, en-1]
    lo0 = min(max(lo0, 0), e0 - 1);  hi0 = min(max(hi0, 0), e0 - 1);
    lo1 = min(max(lo1, 0), e1 - 1);  hi1 = min(max(hi1, 0), e1 - 1);
    lo2 = min(max(lo2, 0), e2 - 1);  hi2 = min(max(hi2, 0), e2 - 1);
    lo3 = min(max(lo3, 0), e3 - 1);  hi3 = min(max(hi3, 0), e3 - 1);

    // hierarchical weight products, order ((wx*wy)*wz)*wt to match jnp.prod axis order
    float pxy[4], pxyz[8], w16[16];
    #pragma unroll
    for (int a = 0; a < 2; ++a)
        #pragma unroll
        for (int b = 0; b < 2; ++b)
            pxy[a * 2 + b] = wx[a] * wy[b];
    #pragma unroll
    for (int a = 0; a < 4; ++a)
        #pragma unroll
        for (int b = 0; b < 2; ++b)
            pxyz[a * 2 + b] = pxy[a] * wz[b];
    #pragma unroll
    for (int a = 0; a < 8; ++a)
        #pragma unroll
        for (int b = 0; b < 2; ++b)
            w16[a * 2 + b] = pxyz[a] * wt[b];

    const float* __restrict__ base = data + (size_t)l * (size_t)T * FDIM;
    float accx = 0.0f, accy = 0.0f;

    if (l >= start_hash) {
        // hash path: xor of 64-bit prime products, mod T via magic multiply
        const unsigned long long hx[2] = { (unsigned long long)(unsigned)lo0,
                                           (unsigned long long)(unsigned)hi0 };
        const unsigned long long hy[2] = { (unsigned long long)(unsigned)lo1 * 19349663ull,
                                           (unsigned long long)(unsigned)hi1 * 19349663ull };
        const unsigned long long hz[2] = { (unsigned long long)(unsigned)lo2 * 83492791ull,
                                           (unsigned long long)(unsigned)hi2 * 83492791ull };
        const unsigned long long ht[2] = { (unsigned long long)(unsigned)lo3 * 73856093ull,
                                           (unsigned long long)(unsigned)hi3 * 73856093ull };
        #pragma unroll
        for (int c = 0; c < 16; ++c) {
            const unsigned long long v =
                hx[(c >> 3) & 1] ^ hy[(c >> 2) & 1] ^ hz[(c >> 1) & 1] ^ ht[c & 1];
            const unsigned long long q = __umul64hi(v, M);   // q in {Q-1, Q}
            unsigned int r = (unsigned int)v - (unsigned int)q * T;  // r in [0, 2T)
            if (r >= T) r -= T;
            const float2 d2 = *(const float2*)(base + (size_t)r * FDIM);
            accx = fmaf(w16[c], d2.x, accx);
            accy = fmaf(w16[c], d2.y, accy);
        }
    } else {
        // direct path: ((x*e1+y)*e2+z)*e3+t, always < T so 32-bit is exact
        #pragma unroll
        for (int c = 0; c < 16; ++c) {
            const unsigned int ix = (unsigned)((c & 8) ? hi0 : lo0);
            const unsigned int iy = (unsigned)((c & 4) ? hi1 : lo1);
            const unsigned int iz = (unsigned)((c & 2) ? hi2 : lo2);
            const unsigned int it = (unsigned)((c & 1) ? hi3 : lo3);
            unsigned int ind = ix * (unsigned)e1 + iy;
            ind = ind * (unsigned)e2 + iz;
            ind = ind * (unsigned)e3 + it;
            const float2 d2 = *(const float2*)(base + (size_t)ind * FDIM);
            accx = fmaf(w16[c], d2.x, accx);
            accy = fmaf(w16[c], d2.y, accy);
        }
    }

    // out[n, l*F .. l*F+1], 8B-aligned coalesced-per-point store
    float2* op = (float2*)(out + ((size_t)n * (size_t)L + (size_t)l) * FDIM);
    *op = make_float2(accx, accy);
}

extern "C" void kernel_launch(void* const* d_in, const int* in_sizes, int n_in,
                              void* d_out, int out_size, void* d_ws, size_t ws_size,
                              hipStream_t stream) {
    const float* xyz    = (const float*)d_in[0];
    const float* tt     = (const float*)d_in[1];
    const float* data   = (const float*)d_in[2];
    const float* bounds = (const float*)d_in[3];
    // d_in[4] = offsets: the 16 binary corners are hard-coded (matches reference OFFSETS)
    const float* es     = (const float*)d_in[5];
    const int*   en     = (const int*)d_in[6];
    const int*   p_sh   = (const int*)d_in[7];
    const int*   p_sf   = (const int*)d_in[8];
    const int*   p_tf   = (const int*)d_in[9];
    float*       out    = (float*)d_out;

    const int N = in_sizes[0] / 3;
    const int L = in_sizes[5] / 4;                       // entrys_size is [L,4]
    const unsigned int T = (unsigned int)(in_sizes[2] / (L * FDIM)); // data is [L,T,F]
    const unsigned long long M = ~0ull / (unsigned long long)T;      // floor(2^64/T), T prime

    const int threads = 256;
    const int blocks_per_level = (N + threads - 1) / threads;
    dim3 grid((unsigned)(blocks_per_level * L));
    mh4d_kernel<<<grid, threads, 0, stream>>>(xyz, tt, data, bounds, es, en,
                                              p_sh, p_sf, p_tf, out,
                                              N, L, T, M);
}

// Round 2
// 281.142 us; speedup vs baseline: 1.4790x; 1.4790x over previous
//
#include <hip/hip_runtime.h>

// MultiHashtable4d: 16-level 4D hash-grid interpolation.
// One thread per (point n, level l); l is wave-uniform so per-level params are
// scalar and the direct/hash branch is uniform.
//
// R2 change: XCD-pinned, level-major block mapping. Each level's hash table is
// T*2*4B = 4.19 MB ~= one XCD's 4 MiB L2. Encoding
//   blockIdx = ((phase*bpl + chunk) * 8) + (l & 7),  phase = l >> 3
// relies on the round-robin XCD = blockIdx % 8 dispatch heuristic: XCD x
// processes level x to completion, then level x+8 — one L2-resident table at a
// time, so gathers hit L2 instead of pulling ~900 MB through the fabric.

#define FDIM 2

__global__ __launch_bounds__(256) void mh4d_kernel(
    const float* __restrict__ xyz,     // [N,3]
    const float* __restrict__ tt,      // [N,1]
    const float* __restrict__ data,    // [L,T,FDIM]
    const float* __restrict__ bounds,  // [2,4]
    const float* __restrict__ es,      // [L,4] entrys_size
    const int*   __restrict__ en,      // [L,4] entrys_num
    const int*   __restrict__ p_sh,    // start_hash
    const int*   __restrict__ p_sf,    // start_frame
    const int*   __restrict__ p_tf,    // total_frame
    float* __restrict__ out,           // [N, L*FDIM]
    int N, int L, unsigned int T, unsigned long long M,
    unsigned int bpl)                  // blocks per level
{
    int l, chunk;
    if ((L & 7) == 0) {
        // XCD-pinned decode: x = b%8 selects the XCD *and* the level group.
        const unsigned int x   = blockIdx.x & 7u;
        const unsigned int rem = blockIdx.x >> 3;
        const unsigned int p   = rem / bpl;      // phase: which level on this XCD
        chunk = (int)(rem - p * bpl);
        l     = (int)(p * 8u + x);
    } else {
        l     = (int)(blockIdx.x / bpl);
        chunk = (int)(blockIdx.x - (unsigned)l * bpl);
    }
    const int n = chunk * (int)blockDim.x + (int)threadIdx.x;
    if (n >= N) return;

    const int start_hash = *p_sh;
    // reference: t - start_frame/(total_frame-1), scalar rounded to f32
    const float tshift = (float)((double)(*p_sf) / (double)(*p_tf - 1));

    // wave-uniform per-level params -> scalar loads
    const float es0 = es[l * 4 + 0], es1 = es[l * 4 + 1];
    const float es2 = es[l * 4 + 2], es3 = es[l * 4 + 3];
    const int e0 = en[l * 4 + 0], e1 = en[l * 4 + 1];
    const int e2 = en[l * 4 + 2], e3 = en[l * 4 + 3];

    const float b0 = bounds[0], b1 = bounds[1], b2 = bounds[2], b3 = bounds[3];

    const float x  = xyz[n * 3 + 0];
    const float y  = xyz[n * 3 + 1];
    const float z  = xyz[n * 3 + 2];
    const float tv = tt[n] - tshift;

    // float_xyzt = (xyzt - bounds[0]) / entrys_size  (IEEE f32 div, matches ref)
    const float f0 = (x  - b0) / es0;
    const float f1 = (y  - b1) / es1;
    const float f2 = (z  - b2) / es2;
    const float f3 = (tv - b3) / es3;

    // Corner ints: trunc(f + offset) computed IN f32 — must NOT fold to trunc(f)+1,
    // because f32 rounding of (f+1.0f) near integers changes the index like the ref does.
    int lo0 = (int)f0, hi0 = (int)(f0 + 1.0f);
    int lo1 = (int)f1, hi1 = (int)(f1 + 1.0f);
    int lo2 = (int)f2, hi2 = (int)(f2 + 1.0f);
    int lo3 = (int)f3, hi3 = (int)(f3 + 1.0f);

    // offsets from UNCLIPPED corner-0 trunc (ref computes offset before clip)
    const float o0 = f0 - (float)lo0;
    const float o1 = f1 - (float)lo1;
    const float o2 = f2 - (float)lo2;
    const float o3 = f3 - (float)lo3;

    // weights: clip(1-o,0,1) / clip(o,0,1)
    const float wx[2] = { fminf(fmaxf(1.0f - o0, 0.0f), 1.0f), fminf(fmaxf(o0, 0.0f), 1.0f) };
    const float wy[2] = { fminf(fmaxf(1.0f - o1, 0.0f), 1.0f), fminf(fmaxf(o1, 0.0f), 1.0f) };
    const float wz[2] = { fminf(fmaxf(1.0f - o2, 0.0f), 1.0f), fminf(fmaxf(o2, 0.0f), 1.0f) };
    const float wt[2] = { fminf(fmaxf(1.0f - o3, 0.0f), 1.0f), fminf(fmaxf(o3, 0.0f), 1.0f) };

    // clip indices to [0, en-1]
    lo0 = min(max(lo0, 0), e0 - 1);  hi0 = min(max(hi0, 0), e0 - 1);
    lo1 = min(max(lo1, 0), e1 - 1);  hi1 = min(max(hi1, 0), e1 - 1);
    lo2 = min(max(lo2, 0), e2 - 1);  hi2 = min(max(hi2, 0), e2 - 1);
    lo3 = min(max(lo3, 0), e3 - 1);  hi3 = min(max(hi3, 0), e3 - 1);

    // hierarchical weight products, order ((wx*wy)*wz)*wt to match jnp.prod axis order
    float pxy[4], pxyz[8], w16[16];
    #pragma unroll
    for (int a = 0; a < 2; ++a)
        #pragma unroll
        for (int b = 0; b < 2; ++b)
            pxy[a * 2 + b] = wx[a] * wy[b];
    #pragma unroll
    for (int a = 0; a < 4; ++a)
        #pragma unroll
        for (int b = 0; b < 2; ++b)
            pxyz[a * 2 + b] = pxy[a] * wz[b];
    #pragma unroll
    for (int a = 0; a < 8; ++a)
        #pragma unroll
        for (int b = 0; b < 2; ++b)
            w16[a * 2 + b] = pxyz[a] * wt[b];

    const float* __restrict__ base = data + (size_t)l * (size_t)T * FDIM;
    float accx = 0.0f, accy = 0.0f;

    if (l >= start_hash) {
        // hash path: xor of 64-bit prime products, mod T via magic multiply
        const unsigned long long hx[2] = { (unsigned long long)(unsigned)lo0,
                                           (unsigned long long)(unsigned)hi0 };
        const unsigned long long hy[2] = { (unsigned long long)(unsigned)lo1 * 19349663ull,
                                           (unsigned long long)(unsigned)hi1 * 19349663ull };
        const unsigned long long hz[2] = { (unsigned long long)(unsigned)lo2 * 83492791ull,
                                           (unsigned long long)(unsigned)hi2 * 83492791ull };
        const unsigned long long ht[2] = { (unsigned long long)(unsigned)lo3 * 73856093ull,
                                           (unsigned long long)(unsigned)hi3 * 73856093ull };
        #pragma unroll
        for (int c = 0; c < 16; ++c) {
            const unsigned long long v =
                hx[(c >> 3) & 1] ^ hy[(c >> 2) & 1] ^ hz[(c >> 1) & 1] ^ ht[c & 1];
            const unsigned long long q = __umul64hi(v, M);   // q in {Q-1, Q}
            unsigned int r = (unsigned int)v - (unsigned int)q * T;  // r in [0, 2T)
            if (r >= T) r -= T;
            const float2 d2 = *(const float2*)(base + (size_t)r * FDIM);
            accx = fmaf(w16[c], d2.x, accx);
            accy = fmaf(w16[c], d2.y, accy);
        }
    } else {
        // direct path: ((x*e1+y)*e2+z)*e3+t, always < T so 32-bit is exact
        #pragma unroll
        for (int c = 0; c < 16; ++c) {
            const unsigned int ix = (unsigned)((c & 8) ? hi0 : lo0);
            const unsigned int iy = (unsigned)((c & 4) ? hi1 : lo1);
            const unsigned int iz = (unsigned)((c & 2) ? hi2 : lo2);
            const unsigned int it = (unsigned)((c & 1) ? hi3 : lo3);
            unsigned int ind = ix * (unsigned)e1 + iy;
            ind = ind * (unsigned)e2 + iz;
            ind = ind * (unsigned)e3 + it;
            const float2 d2 = *(const float2*)(base + (size_t)ind * FDIM);
            accx = fmaf(w16[c], d2.x, accx);
            accy = fmaf(w16[c], d2.y, accy);
        }
    }

    // out[n, l*F .. l*F+1], 8B-aligned store
    float2* op = (float2*)(out + ((size_t)n * (size_t)L + (size_t)l) * FDIM);
    *op = make_float2(accx, accy);
}

extern "C" void kernel_launch(void* const* d_in, const int* in_sizes, int n_in,
                              void* d_out, int out_size, void* d_ws, size_t ws_size,
                              hipStream_t stream) {
    const float* xyz    = (const float*)d_in[0];
    const float* tt     = (const float*)d_in[1];
    const float* data   = (const float*)d_in[2];
    const float* bounds = (const float*)d_in[3];
    // d_in[4] = offsets: the 16 binary corners are hard-coded (matches reference OFFSETS)
    const float* es     = (const float*)d_in[5];
    const int*   en     = (const int*)d_in[6];
    const int*   p_sh   = (const int*)d_in[7];
    const int*   p_sf   = (const int*)d_in[8];
    const int*   p_tf   = (const int*)d_in[9];
    float*       out    = (float*)d_out;

    const int N = in_sizes[0] / 3;
    const int L = in_sizes[5] / 4;                       // entrys_size is [L,4]
    const unsigned int T = (unsigned int)(in_sizes[2] / (L * FDIM)); // data is [L,T,F]
    const unsigned long long M = ~0ull / (unsigned long long)T;      // floor(2^64/T), T prime

    const int threads = 256;
    const unsigned int bpl = (unsigned)((N + threads - 1) / threads); // blocks per level
    dim3 grid(bpl * (unsigned)L);
    mh4d_kernel<<<grid, threads, 0, stream>>>(xyz, tt, data, bounds, es, en,
                                              p_sh, p_sf, p_tf, out,
                                              N, L, T, M, bpl);
}

// Round 3
// 279.628 us; speedup vs baseline: 1.4870x; 1.0054x over previous
//
#include <hip/hip_runtime.h>

// MultiHashtable4d: 16-level 4D hash-grid interpolation.
// One thread per (point n, level l); l is wave-uniform so per-level params are
// scalar and the direct/hash branch is uniform.
//
// R2: XCD-pinned level-major mapping (blockIdx%8 == level%8) keeps one 4.19MB
//     table per XCD-L2 -> FETCH 902->242MB.
// R3: force memory-level parallelism. Explicit phases: compute all 16 table
//     offsets -> issue all 16 float2 loads into a live vals[] array -> compute
//     weights (VALU overlaps load latency) -> FMA reduction. Costs ~32 extra
//     VGPRs on purpose; at ~24 waves/CU x 16 outstanding loads we can saturate
//     the L1's ~1 line/cy divergent-gather service rate instead of ~30% of it.

#define FDIM 2

__global__ __launch_bounds__(256) void mh4d_kernel(
    const float* __restrict__ xyz,     // [N,3]
    const float* __restrict__ tt,      // [N,1]
    const float* __restrict__ data,    // [L,T,FDIM]
    const float* __restrict__ bounds,  // [2,4]
    const float* __restrict__ es,      // [L,4] entrys_size
    const int*   __restrict__ en,      // [L,4] entrys_num
    const int*   __restrict__ p_sh,    // start_hash
    const int*   __restrict__ p_sf,    // start_frame
    const int*   __restrict__ p_tf,    // total_frame
    float* __restrict__ out,           // [N, L*FDIM]
    int N, int L, unsigned int T, unsigned long long M,
    unsigned int bpl)                  // blocks per level
{
    int l, chunk;
    if ((L & 7) == 0) {
        // XCD-pinned decode: x = b%8 selects the XCD *and* the level group.
        const unsigned int x   = blockIdx.x & 7u;
        const unsigned int rem = blockIdx.x >> 3;
        const unsigned int p   = rem / bpl;      // phase: which level on this XCD
        chunk = (int)(rem - p * bpl);
        l     = (int)(p * 8u + x);
    } else {
        l     = (int)(blockIdx.x / bpl);
        chunk = (int)(blockIdx.x - (unsigned)l * bpl);
    }
    const int n = chunk * (int)blockDim.x + (int)threadIdx.x;
    if (n >= N) return;

    const int start_hash = *p_sh;
    // reference: t - start_frame/(total_frame-1), scalar rounded to f32
    const float tshift = (float)((double)(*p_sf) / (double)(*p_tf - 1));

    // wave-uniform per-level params -> scalar loads
    const float es0 = es[l * 4 + 0], es1 = es[l * 4 + 1];
    const float es2 = es[l * 4 + 2], es3 = es[l * 4 + 3];
    const int e0 = en[l * 4 + 0], e1 = en[l * 4 + 1];
    const int e2 = en[l * 4 + 2], e3 = en[l * 4 + 3];

    const float b0 = bounds[0], b1 = bounds[1], b2 = bounds[2], b3 = bounds[3];

    const float x  = xyz[n * 3 + 0];
    const float y  = xyz[n * 3 + 1];
    const float z  = xyz[n * 3 + 2];
    const float tv = tt[n] - tshift;

    // float_xyzt = (xyzt - bounds[0]) / entrys_size  (IEEE f32 div, matches ref)
    const float f0 = (x  - b0) / es0;
    const float f1 = (y  - b1) / es1;
    const float f2 = (z  - b2) / es2;
    const float f3 = (tv - b3) / es3;

    // Corner ints: trunc(f + offset) computed IN f32 — must NOT fold to trunc(f)+1,
    // because f32 rounding of (f+1.0f) near integers changes the index like the ref does.
    int lo0 = (int)f0, hi0 = (int)(f0 + 1.0f);
    int lo1 = (int)f1, hi1 = (int)(f1 + 1.0f);
    int lo2 = (int)f2, hi2 = (int)(f2 + 1.0f);
    int lo3 = (int)f3, hi3 = (int)(f3 + 1.0f);

    // offsets from UNCLIPPED corner-0 trunc (ref computes offset before clip)
    const float o0 = f0 - (float)lo0;
    const float o1 = f1 - (float)lo1;
    const float o2 = f2 - (float)lo2;
    const float o3 = f3 - (float)lo3;

    // clip indices to [0, en-1]
    lo0 = min(max(lo0, 0), e0 - 1);  hi0 = min(max(hi0, 0), e0 - 1);
    lo1 = min(max(lo1, 0), e1 - 1);  hi1 = min(max(hi1, 0), e1 - 1);
    lo2 = min(max(lo2, 0), e2 - 1);  hi2 = min(max(hi2, 0), e2 - 1);
    lo3 = min(max(lo3, 0), e3 - 1);  hi3 = min(max(hi3, 0), e3 - 1);

    // ---- Phase 1: all 16 table offsets (elements, not bytes) ----
    unsigned int r16[16];
    if (l >= start_hash) {
        // hash path: xor of 64-bit prime products, mod T via magic multiply
        const unsigned long long hx[2] = { (unsigned long long)(unsigned)lo0,
                                           (unsigned long long)(unsigned)hi0 };
        const unsigned long long hy[2] = { (unsigned long long)(unsigned)lo1 * 19349663ull,
                                           (unsigned long long)(unsigned)hi1 * 19349663ull };
        const unsigned long long hz[2] = { (unsigned long long)(unsigned)lo2 * 83492791ull,
                                           (unsigned long long)(unsigned)hi2 * 83492791ull };
        const unsigned long long ht[2] = { (unsigned long long)(unsigned)lo3 * 73856093ull,
                                           (unsigned long long)(unsigned)hi3 * 73856093ull };
        #pragma unroll
        for (int c = 0; c < 16; ++c) {
            const unsigned long long v =
                hx[(c >> 3) & 1] ^ hy[(c >> 2) & 1] ^ hz[(c >> 1) & 1] ^ ht[c & 1];
            const unsigned long long q = __umul64hi(v, M);   // q in {Q-1, Q}
            unsigned int r = (unsigned int)v - (unsigned int)q * T;  // r in [0, 2T)
            if (r >= T) r -= T;
            r16[c] = r;
        }
    } else {
        // direct path: ((x*e1+y)*e2+z)*e3+t, always < T so 32-bit is exact
        #pragma unroll
        for (int c = 0; c < 16; ++c) {
            const unsigned int ix = (unsigned)((c & 8) ? hi0 : lo0);
            const unsigned int iy = (unsigned)((c & 4) ? hi1 : lo1);
            const unsigned int iz = (unsigned)((c & 2) ? hi2 : lo2);
            const unsigned int it = (unsigned)((c & 1) ? hi3 : lo3);
            unsigned int ind = ix * (unsigned)e1 + iy;
            ind = ind * (unsigned)e2 + iz;
            ind = ind * (unsigned)e3 + it;
            r16[c] = ind;
        }
    }

    // ---- Phase 2: issue ALL 16 gathers; keep them live so 16 loads are in
    // flight per wave before the first consumer waits. ----
    const float* __restrict__ base = data + (size_t)l * (size_t)T * FDIM;
    float2 vals[16];
    #pragma unroll
    for (int c = 0; c < 16; ++c)
        vals[c] = *(const float2*)(base + (size_t)r16[c] * FDIM);

    // ---- Phase 3: weights (VALU work overlapping the in-flight loads) ----
    // clip(1-o,0,1) / clip(o,0,1); hierarchical products ((wx*wy)*wz)*wt
    const float wx[2] = { fminf(fmaxf(1.0f - o0, 0.0f), 1.0f), fminf(fmaxf(o0, 0.0f), 1.0f) };
    const float wy[2] = { fminf(fmaxf(1.0f - o1, 0.0f), 1.0f), fminf(fmaxf(o1, 0.0f), 1.0f) };
    const float wz[2] = { fminf(fmaxf(1.0f - o2, 0.0f), 1.0f), fminf(fmaxf(o2, 0.0f), 1.0f) };
    const float wt[2] = { fminf(fmaxf(1.0f - o3, 0.0f), 1.0f), fminf(fmaxf(o3, 0.0f), 1.0f) };

    float pxy[4], pxyz[8], w16[16];
    #pragma unroll
    for (int a = 0; a < 2; ++a)
        #pragma unroll
        for (int b = 0; b < 2; ++b)
            pxy[a * 2 + b] = wx[a] * wy[b];
    #pragma unroll
    for (int a = 0; a < 4; ++a)
        #pragma unroll
        for (int b = 0; b < 2; ++b)
            pxyz[a * 2 + b] = pxy[a] * wz[b];
    #pragma unroll
    for (int a = 0; a < 8; ++a)
        #pragma unroll
        for (int b = 0; b < 2; ++b)
            w16[a * 2 + b] = pxyz[a] * wt[b];

    // ---- Phase 4: reduction, consuming loads in completion order ----
    float accx = 0.0f, accy = 0.0f;
    #pragma unroll
    for (int c = 0; c < 16; ++c) {
        accx = fmaf(w16[c], vals[c].x, accx);
        accy = fmaf(w16[c], vals[c].y, accy);
    }

    // out[n, l*F .. l*F+1], 8B-aligned store
    float2* op = (float2*)(out + ((size_t)n * (size_t)L + (size_t)l) * FDIM);
    *op = make_float2(accx, accy);
}

extern "C" void kernel_launch(void* const* d_in, const int* in_sizes, int n_in,
                              void* d_out, int out_size, void* d_ws, size_t ws_size,
                              hipStream_t stream) {
    const float* xyz    = (const float*)d_in[0];
    const float* tt     = (const float*)d_in[1];
    const float* data   = (const float*)d_in[2];
    const float* bounds = (const float*)d_in[3];
    // d_in[4] = offsets: the 16 binary corners are hard-coded (matches reference OFFSETS)
    const float* es     = (const float*)d_in[5];
    const int*   en     = (const int*)d_in[6];
    const int*   p_sh   = (const int*)d_in[7];
    const int*   p_sf   = (const int*)d_in[8];
    const int*   p_tf   = (const int*)d_in[9];
    float*       out    = (float*)d_out;

    const int N = in_sizes[0] / 3;
    const int L = in_sizes[5] / 4;                       // entrys_size is [L,4]
    const unsigned int T = (unsigned int)(in_sizes[2] / (L * FDIM)); // data is [L,T,F]
    const unsigned long long M = ~0ull / (unsigned long long)T;      // floor(2^64/T), T prime

    const int threads = 256;
    const unsigned int bpl = (unsigned)((N + threads - 1) / threads); // blocks per level
    dim3 grid(bpl * (unsigned)L);
    mh4d_kernel<<<grid, threads, 0, stream>>>(xyz, tt, data, bounds, es, en,
                                              p_sh, p_sf, p_tf, out,
                                              N, L, T, M, bpl);
}

// Round 4
// 267.786 us; speedup vs baseline: 1.5528x; 1.0442x over previous
//
#include <hip/hip_runtime.h>

// MultiHashtable4d: 16-level 4D hash-grid interpolation.
// One thread per (point n, level l); l is wave-uniform so per-level params are
// scalar and the direct/hash branch is uniform.
//
// R2: XCD-pinned level-major mapping (blockIdx%8 == level%8) keeps one 4.19MB
//     table per XCD-L2 -> FETCH 902->242MB, 321->193us.
// R3: explicit phase structure (addresses -> 16 live loads -> weights -> FMA).
//     Neutral: cap is a shared per-CU resource (MSHR x latency), not per-wave MLP.
// R4: the table (4.194MB) exactly fits one XCD L2 (4.194MB). Streaming traffic
//     (xyz/t reads, out writes) was evicting table lines: FETCH 215MB vs 67MB
//     compulsory. L2-miss gathers dwell ~900cy in an MSHR vs ~220cy for hits,
//     so 10% misses eat ~30% of MSHR-seconds. Mark all streaming accesses
//     nontemporal so the table owns L2; gathers stay cached.

#define FDIM 2

__global__ __launch_bounds__(256) void mh4d_kernel(
    const float* __restrict__ xyz,     // [N,3]
    const float* __restrict__ tt,      // [N,1]
    const float* __restrict__ data,    // [L,T,FDIM]
    const float* __restrict__ bounds,  // [2,4]
    const float* __restrict__ es,      // [L,4] entrys_size
    const int*   __restrict__ en,      // [L,4] entrys_num
    const int*   __restrict__ p_sh,    // start_hash
    const int*   __restrict__ p_sf,    // start_frame
    const int*   __restrict__ p_tf,    // total_frame
    float* __restrict__ out,           // [N, L*FDIM]
    int N, int L, unsigned int T, unsigned long long M,
    unsigned int bpl)                  // blocks per level
{
    int l, chunk;
    if ((L & 7) == 0) {
        // XCD-pinned decode: x = b%8 selects the XCD *and* the level group.
        const unsigned int x   = blockIdx.x & 7u;
        const unsigned int rem = blockIdx.x >> 3;
        const unsigned int p   = rem / bpl;      // phase: which level on this XCD
        chunk = (int)(rem - p * bpl);
        l     = (int)(p * 8u + x);
    } else {
        l     = (int)(blockIdx.x / bpl);
        chunk = (int)(blockIdx.x - (unsigned)l * bpl);
    }
    const int n = chunk * (int)blockDim.x + (int)threadIdx.x;
    if (n >= N) return;

    const int start_hash = *p_sh;
    // reference: t - start_frame/(total_frame-1), scalar rounded to f32
    const float tshift = (float)((double)(*p_sf) / (double)(*p_tf - 1));

    // wave-uniform per-level params -> scalar loads
    const float es0 = es[l * 4 + 0], es1 = es[l * 4 + 1];
    const float es2 = es[l * 4 + 2], es3 = es[l * 4 + 3];
    const int e0 = en[l * 4 + 0], e1 = en[l * 4 + 1];
    const int e2 = en[l * 4 + 2], e3 = en[l * 4 + 3];

    const float b0 = bounds[0], b1 = bounds[1], b2 = bounds[2], b3 = bounds[3];

    // streaming inputs: nontemporal — do not let them evict table lines in L2
    const float x  = __builtin_nontemporal_load(&xyz[n * 3 + 0]);
    const float y  = __builtin_nontemporal_load(&xyz[n * 3 + 1]);
    const float z  = __builtin_nontemporal_load(&xyz[n * 3 + 2]);
    const float tv = __builtin_nontemporal_load(&tt[n]) - tshift;

    // float_xyzt = (xyzt - bounds[0]) / entrys_size  (IEEE f32 div, matches ref)
    const float f0 = (x  - b0) / es0;
    const float f1 = (y  - b1) / es1;
    const float f2 = (z  - b2) / es2;
    const float f3 = (tv - b3) / es3;

    // Corner ints: trunc(f + offset) computed IN f32 — must NOT fold to trunc(f)+1,
    // because f32 rounding of (f+1.0f) near integers changes the index like the ref does.
    int lo0 = (int)f0, hi0 = (int)(f0 + 1.0f);
    int lo1 = (int)f1, hi1 = (int)(f1 + 1.0f);
    int lo2 = (int)f2, hi2 = (int)(f2 + 1.0f);
    int lo3 = (int)f3, hi3 = (int)(f3 + 1.0f);

    // offsets from UNCLIPPED corner-0 trunc (ref computes offset before clip)
    const float o0 = f0 - (float)lo0;
    const float o1 = f1 - (float)lo1;
    const float o2 = f2 - (float)lo2;
    const float o3 = f3 - (float)lo3;

    // clip indices to [0, en-1]
    lo0 = min(max(lo0, 0), e0 - 1);  hi0 = min(max(hi0, 0), e0 - 1);
    lo1 = min(max(lo1, 0), e1 - 1);  hi1 = min(max(hi1, 0), e1 - 1);
    lo2 = min(max(lo2, 0), e2 - 1);  hi2 = min(max(hi2, 0), e2 - 1);
    lo3 = min(max(lo3, 0), e3 - 1);  hi3 = min(max(hi3, 0), e3 - 1);

    // ---- Phase 1: all 16 table offsets (elements, not bytes) ----
    unsigned int r16[16];
    if (l >= start_hash) {
        // hash path: xor of 64-bit prime products, mod T via magic multiply
        const unsigned long long hx[2] = { (unsigned long long)(unsigned)lo0,
                                           (unsigned long long)(unsigned)hi0 };
        const unsigned long long hy[2] = { (unsigned long long)(unsigned)lo1 * 19349663ull,
                                           (unsigned long long)(unsigned)hi1 * 19349663ull };
        const unsigned long long hz[2] = { (unsigned long long)(unsigned)lo2 * 83492791ull,
                                           (unsigned long long)(unsigned)hi2 * 83492791ull };
        const unsigned long long ht[2] = { (unsigned long long)(unsigned)lo3 * 73856093ull,
                                           (unsigned long long)(unsigned)hi3 * 73856093ull };
        #pragma unroll
        for (int c = 0; c < 16; ++c) {
            const unsigned long long v =
                hx[(c >> 3) & 1] ^ hy[(c >> 2) & 1] ^ hz[(c >> 1) & 1] ^ ht[c & 1];
            const unsigned long long q = __umul64hi(v, M);   // q in {Q-1, Q}
            unsigned int r = (unsigned int)v - (unsigned int)q * T;  // r in [0, 2T)
            if (r >= T) r -= T;
            r16[c] = r;
        }
    } else {
        // direct path: ((x*e1+y)*e2+z)*e3+t, always < T so 32-bit is exact
        #pragma unroll
        for (int c = 0; c < 16; ++c) {
            const unsigned int ix = (unsigned)((c & 8) ? hi0 : lo0);
            const unsigned int iy = (unsigned)((c & 4) ? hi1 : lo1);
            const unsigned int iz = (unsigned)((c & 2) ? hi2 : lo2);
            const unsigned int it = (unsigned)((c & 1) ? hi3 : lo3);
            unsigned int ind = ix * (unsigned)e1 + iy;
            ind = ind * (unsigned)e2 + iz;
            ind = ind * (unsigned)e3 + it;
            r16[c] = ind;
        }
    }

    // ---- Phase 2: issue ALL 16 gathers (normal/cached — table must live in L2) ----
    const float* __restrict__ base = data + (size_t)l * (size_t)T * FDIM;
    float2 vals[16];
    #pragma unroll
    for (int c = 0; c < 16; ++c)
        vals[c] = *(const float2*)(base + (size_t)r16[c] * FDIM);

    // ---- Phase 3: weights (VALU work overlapping the in-flight loads) ----
    // clip(1-o,0,1) / clip(o,0,1); hierarchical products ((wx*wy)*wz)*wt
    const float wx[2] = { fminf(fmaxf(1.0f - o0, 0.0f), 1.0f), fminf(fmaxf(o0, 0.0f), 1.0f) };
    const float wy[2] = { fminf(fmaxf(1.0f - o1, 0.0f), 1.0f), fminf(fmaxf(o1, 0.0f), 1.0f) };
    const float wz[2] = { fminf(fmaxf(1.0f - o2, 0.0f), 1.0f), fminf(fmaxf(o2, 0.0f), 1.0f) };
    const float wt[2] = { fminf(fmaxf(1.0f - o3, 0.0f), 1.0f), fminf(fmaxf(o3, 0.0f), 1.0f) };

    float pxy[4], pxyz[8], w16[16];
    #pragma unroll
    for (int a = 0; a < 2; ++a)
        #pragma unroll
        for (int b = 0; b < 2; ++b)
            pxy[a * 2 + b] = wx[a] * wy[b];
    #pragma unroll
    for (int a = 0; a < 4; ++a)
        #pragma unroll
        for (int b = 0; b < 2; ++b)
            pxyz[a * 2 + b] = pxy[a] * wz[b];
    #pragma unroll
    for (int a = 0; a < 8; ++a)
        #pragma unroll
        for (int b = 0; b < 2; ++b)
            w16[a * 2 + b] = pxyz[a] * wt[b];

    // ---- Phase 4: reduction, consuming loads in completion order ----
    float accx = 0.0f, accy = 0.0f;
    #pragma unroll
    for (int c = 0; c < 16; ++c) {
        accx = fmaf(w16[c], vals[c].x, accx);
        accy = fmaf(w16[c], vals[c].y, accy);
    }

    // out[n, l*F .. l*F+1]: nontemporal 8B store — don't pollute L2 with output
    unsigned long long packed =
        ((unsigned long long)__float_as_uint(accy) << 32) | (unsigned long long)__float_as_uint(accx);
    unsigned long long* op =
        (unsigned long long*)(out + ((size_t)n * (size_t)L + (size_t)l) * FDIM);
    __builtin_nontemporal_store(packed, op);
}

extern "C" void kernel_launch(void* const* d_in, const int* in_sizes, int n_in,
                              void* d_out, int out_size, void* d_ws, size_t ws_size,
                              hipStream_t stream) {
    const float* xyz    = (const float*)d_in[0];
    const float* tt     = (const float*)d_in[1];
    const float* data   = (const float*)d_in[2];
    const float* bounds = (const float*)d_in[3];
    // d_in[4] = offsets: the 16 binary corners are hard-coded (matches reference OFFSETS)
    const float* es     = (const float*)d_in[5];
    const int*   en     = (const int*)d_in[6];
    const int*   p_sh   = (const int*)d_in[7];
    const int*   p_sf   = (const int*)d_in[8];
    const int*   p_tf   = (const int*)d_in[9];
    float*       out    = (float*)d_out;

    const int N = in_sizes[0] / 3;
    const int L = in_sizes[5] / 4;                       // entrys_size is [L,4]
    const unsigned int T = (unsigned int)(in_sizes[2] / (L * FDIM)); // data is [L,T,F]
    const unsigned long long M = ~0ull / (unsigned long long)T;      // floor(2^64/T), T prime

    const int threads = 256;
    const unsigned int bpl = (unsigned)((N + threads - 1) / threads); // blocks per level
    dim3 grid(bpl * (unsigned)L);
    mh4d_kernel<<<grid, threads, 0, stream>>>(xyz, tt, data, bounds, es, en,
                                              p_sh, p_sf, p_tf, out,
                                              N, L, T, M, bpl);
}